// Round 5
// baseline (70.760 us; speedup 1.0000x reference)
//
#include <hip/hip_runtime.h>

#define BB 4
#define CC 64
#define C2 32            // channel pairs
#define HH 64
#define WW 64
#define PATCH 9
#define HALF 4
#define P2 81
#define HW (HH * WW)     // 4096
#define IMG (CC * HW)    // floats per batch-image

typedef _Float16 v2h __attribute__((ext_vector_type(2)));

// ws layout (dwords): nf[img][b][c2][p], p = y*64+x
//   c2 stride 4096, b stride 131072, img stride 524288  (4 MB total)
// Each dword = {f16(ch 2*c2), f16(ch 2*c2+1)} of the L2-NORMALIZED feature.

__global__ __launch_bounds__(128) void prep_kernel(const float* __restrict__ f1,
                                                   const float* __restrict__ f2,
                                                   unsigned* __restrict__ nf) {
    int gid = blockIdx.x * 128 + threadIdx.x;    // 0..32767
    int img = gid >> 14;
    int b   = (gid >> 12) & 3;
    int p   = gid & 4095;
    const float* src = (img ? f2 : f1) + b * IMG + p;
    float v[CC];
    float ss = 0.f;
#pragma unroll
    for (int c = 0; c < CC; ++c) { float t = src[c * HW]; v[c] = t; ss += t * t; }
    float inv = rsqrtf(ss + 1e-6f);
    unsigned* dst = nf + img * 524288 + b * 131072 + p;
#pragma unroll
    for (int c2 = 0; c2 < C2; ++c2) {
        v2h h = { (_Float16)(v[2 * c2] * inv), (_Float16)(v[2 * c2 + 1] * inv) };
        dst[c2 * 4096] = __builtin_bit_cast(unsigned, h);
    }
}

// One block per (b, y): 256 blocks, 576 threads = (x:64, dy:9).
// Stage f2 rows y-4..y+4 (packed f16 pairs, x-major, zero-padded cols/rows) +
// f1 row y; single barrier; 9 dx taps per thread via v_dot2_f32_f16.
__global__ __launch_bounds__(576) void corr_kernel(const unsigned* __restrict__ nf,
                                                   float* __restrict__ out) {
    __shared__ unsigned sB[PATCH * C2 * 72];   // [dy][c2][72 cols] pads at 0..3,68..71 (82.9 KB)
    __shared__ unsigned sA[C2 * 64];           // [c2][x] f1 row (8 KB)

    const int tid = threadIdx.x;
    const int x  = tid & 63;
    const int dy = tid >> 6;                   // 0..8
    const int b  = blockIdx.x >> 6;
    const int y  = blockIdx.x & 63;

    const unsigned* nf1b = nf + b * 131072;
    const unsigned* nf2b = nf + 524288 + b * 131072;

    // stage sA: 512 uint4 items
    if (tid < 512) {
        int c2 = tid >> 4, k = tid & 15;
        *(uint4*)&sA[c2 * 64 + k * 4] = *(const uint4*)&nf1b[c2 * 4096 + y * 64 + k * 4];
    }
    // stage sB: 4608 uint4 items (8 per thread); invalid rows -> zeros
#pragma unroll
    for (int it = 0; it < 8; ++it) {
        int item = tid + it * 576;
        int dyy = item >> 9;                   // 0..8
        int rem = item & 511;
        int c2 = rem >> 4, k = rem & 15;
        int y2 = y + dyy - HALF;
        uint4 vv = {0u, 0u, 0u, 0u};
        if ((unsigned)y2 < HH)
            vv = *(const uint4*)&nf2b[c2 * 4096 + y2 * 64 + k * 4];
        *(uint4*)&sB[(dyy * C2 + c2) * 72 + 4 + k * 4] = vv;
    }
    // zero pads: 288 rows x 8 cols = 2304 dwords
#pragma unroll
    for (int j = tid; j < 2304; j += 576) {
        int row = j >> 3, e = j & 7;
        sB[row * 72 + (e < 4 ? e : 64 + e)] = 0u;
    }
    __syncthreads();

    float acc[PATCH];
#pragma unroll
    for (int i = 0; i < PATCH; ++i) acc[i] = 0.f;

#pragma unroll
    for (int c2 = 0; c2 < C2; ++c2) {
        v2h a2 = __builtin_bit_cast(v2h, sA[c2 * 64 + x]);
        const unsigned* br = &sB[(dy * C2 + c2) * 72 + x];   // padded col of tap dx = x+dx
#pragma unroll
        for (int dx = 0; dx < PATCH; ++dx)
            acc[dx] = __builtin_amdgcn_fdot2(a2, __builtin_bit_cast(v2h, br[dx]),
                                             acc[dx], false);
    }

    float* ob = out + b * P2 * HW + y * WW + x;
#pragma unroll
    for (int dx = 0; dx < PATCH; ++dx)
        ob[(dy * PATCH + dx) * HW] = fmaxf(acc[dx], 0.f);
}

extern "C" void kernel_launch(void* const* d_in, const int* in_sizes, int n_in,
                              void* d_out, int out_size, void* d_ws, size_t ws_size,
                              hipStream_t stream) {
    const float* f1 = (const float*)d_in[0];
    const float* f2 = (const float*)d_in[1];
    float* out = (float*)d_out;
    unsigned* nf = (unsigned*)d_ws;   // 4 MB used

    prep_kernel<<<256, 128, 0, stream>>>(f1, f2, nf);
    corr_kernel<<<BB * HH, 576, 0, stream>>>(nf, out);
}

// Round 6
// 70.337 us; speedup vs baseline: 1.0060x; 1.0060x over previous
//
#include <hip/hip_runtime.h>

#define BB 4
#define CC 64
#define C2 32            // channel pairs
#define HH 64
#define WW 64
#define PATCH 9
#define HALF 4
#define P2 81
#define HW 4096
#define IMG (CC * HW)

typedef _Float16 v2h __attribute__((ext_vector_type(2)));

static __device__ __forceinline__ unsigned pk(float a, float b) {
    v2h h = {(_Float16)a, (_Float16)b};
    return __builtin_bit_cast(unsigned, h);
}

// Single fused kernel: stage raw->f16x2 in LDS, column L2-norms from LDS,
// 9x9 correlation via v_dot2_f32_f16, ReLU. One block per (b,y).
__global__ __launch_bounds__(576) void corr_kernel(const float* __restrict__ f1,
                                                   const float* __restrict__ f2,
                                                   float* __restrict__ out) {
    __shared__ unsigned sB[PATCH * C2 * 72];  // [dy][c2][72]; cols 0..3,68..71 zero (82.9 KB)
    __shared__ unsigned sA[C2 * 64];          // [c2][x] f1 row (8 KB)
    __shared__ float sS2[PATCH * 72];         // f2 col inv-norms per halo row
    __shared__ float sS1[64];                 // f1 col inv-norms

    const int tid = threadIdx.x;
    const int x  = tid & 63;
    const int dy = tid >> 6;                  // 0..8
    const int b  = blockIdx.x >> 6;
    const int y  = blockIdx.x & 63;

    const float* f1r = f1 + b * IMG + y * WW;
    const float* f2b = f2 + b * IMG;

    // ---- stage f1 row: 512 items (c2, k), two float4 -> one uint4 ----
    if (tid < 512) {
        int c2 = tid >> 4, k = tid & 15;
        float4 va = *(const float4*)(f1r + (2 * c2) * HW + 4 * k);
        float4 vb = *(const float4*)(f1r + (2 * c2 + 1) * HW + 4 * k);
        uint4 u = {pk(va.x, vb.x), pk(va.y, vb.y), pk(va.z, vb.z), pk(va.w, vb.w)};
        *(uint4*)&sA[c2 * 64 + 4 * k] = u;
    }
    // ---- stage f2 halo: 4608 items (dyy, c2, k); invalid rows -> zeros ----
#pragma unroll
    for (int it = 0; it < 8; ++it) {
        int item = tid + it * 576;
        int dyy = item >> 9;
        int rem = item & 511;
        int c2 = rem >> 4, k = rem & 15;
        int y2 = y + dyy - HALF;
        uint4 u = {0u, 0u, 0u, 0u};
        if ((unsigned)y2 < HH) {
            const float* p = f2b + y2 * WW + 4 * k;
            float4 va = *(const float4*)(p + (2 * c2) * HW);
            float4 vb = *(const float4*)(p + (2 * c2 + 1) * HW);
            u.x = pk(va.x, vb.x); u.y = pk(va.y, vb.y);
            u.z = pk(va.z, vb.z); u.w = pk(va.w, vb.w);
        }
        *(uint4*)&sB[(dyy * C2 + c2) * 72 + 4 + 4 * k] = u;
    }
    // ---- zero pads: 288 rows x 8 cols ----
#pragma unroll
    for (int j = tid; j < 2304; j += 576) {
        int row = j >> 3, e = j & 7;
        sB[row * 72 + (e < 4 ? e : 64 + e)] = 0u;
    }
    __syncthreads();

    // ---- column inverse norms: 648 sB cols + 64 sA cols ----
    for (int t = tid; t < 712; t += 576) {
        float ss = 0.f;
        if (t < 648) {
            int row = t / 72, col = t - row * 72;
            const unsigned* p = &sB[row * C2 * 72 + col];
#pragma unroll
            for (int c2 = 0; c2 < C2; ++c2) {
                v2h v = __builtin_bit_cast(v2h, p[c2 * 72]);
                ss = __builtin_amdgcn_fdot2(v, v, ss, false);
            }
            sS2[t] = rsqrtf(ss + 1e-6f);
        } else {
            int col = t - 648;
            const unsigned* p = &sA[col];
#pragma unroll
            for (int c2 = 0; c2 < C2; ++c2) {
                v2h v = __builtin_bit_cast(v2h, p[c2 * 64]);
                ss = __builtin_amdgcn_fdot2(v, v, ss, false);
            }
            sS1[col] = rsqrtf(ss + 1e-6f);
        }
    }
    __syncthreads();

    // ---- main loop: 32 c2 x 9 taps, v_dot2_f32_f16 ----
    float acc[PATCH];
#pragma unroll
    for (int i = 0; i < PATCH; ++i) acc[i] = 0.f;
#pragma unroll
    for (int c2 = 0; c2 < C2; ++c2) {
        v2h a2 = __builtin_bit_cast(v2h, sA[c2 * 64 + x]);
        const unsigned* br = &sB[(dy * C2 + c2) * 72 + x];  // tap dx -> padded col x+dx
#pragma unroll
        for (int dx = 0; dx < PATCH; ++dx)
            acc[dx] = __builtin_amdgcn_fdot2(a2, __builtin_bit_cast(v2h, br[dx]),
                                             acc[dx], false);
    }

    const float s1 = sS1[x];
    float* ob = out + b * P2 * HW + y * WW + x;
#pragma unroll
    for (int dx = 0; dx < PATCH; ++dx)
        ob[(dy * PATCH + dx) * HW] = fmaxf(acc[dx] * s1 * sS2[dy * 72 + x + dx], 0.f);
}

extern "C" void kernel_launch(void* const* d_in, const int* in_sizes, int n_in,
                              void* d_out, int out_size, void* d_ws, size_t ws_size,
                              hipStream_t stream) {
    const float* f1 = (const float*)d_in[0];
    const float* f2 = (const float*)d_in[1];
    float* out = (float*)d_out;
    (void)d_ws; (void)ws_size;

    corr_kernel<<<BB * HH, 576, 0, stream>>>(f1, f2, out);
}

// Round 7
// 67.875 us; speedup vs baseline: 1.0425x; 1.0363x over previous
//
#include <hip/hip_runtime.h>

#define BB 4
#define CC 64
#define C2 32            // channel pairs
#define HH 64
#define WW 64
#define PATCH 9
#define HALF 4
#define P2 81
#define HW 4096
#define IMG (CC * HW)

typedef _Float16 v2h __attribute__((ext_vector_type(2)));

static __device__ __forceinline__ unsigned pk(float a, float b) {
    v2h h = {(_Float16)a, (_Float16)b};
    return __builtin_bit_cast(unsigned, h);
}

// One SINGLE-WAVE block per (b, y, dy): 2304 blocks x 64 threads.
// f1 row in registers (packed f16 pairs), f2 row staged packed in 9.2 KB LDS.
// No cross-wave barriers anywhere; 9 independent waves/CU.
// dy is the fastest grid dim -> the 9 blocks reading the same f2 row have
// blockIdx stride 8 -> same XCD (round-robin %8) -> L2 reuse.
__global__ __launch_bounds__(64) void corr_kernel(const float* __restrict__ f1,
                                                  const float* __restrict__ f2,
                                                  float* __restrict__ out) {
    __shared__ unsigned sB[C2 * 72];   // [c2][72 cols]; cols 0..3,68..71 zero (9.2 KB)
    __shared__ float sS2[64];          // f2 column inverse norms (real cols)

    const int x   = threadIdx.x;       // 0..63
    const int bid = blockIdx.x;        // ((b*64 + y)*9 + dy)
    const int dy  = bid % PATCH;
    const int y   = (bid / PATCH) & 63;
    const int b   = bid / (PATCH * HH);
    const int y2  = y + dy - HALF;

    float* ob = out + b * (P2 * HW) + y * WW + x;

    if ((unsigned)y2 >= HH) {          // whole dy-row out of bounds -> zeros
#pragma unroll
        for (int dx = 0; dx < PATCH; ++dx)
            ob[(dy * PATCH + dx) * HW] = 0.f;
        return;
    }

    // ---- f1 row -> registers: packed f16 pairs + fp32 sumsq ----
    const float* f1r = f1 + b * IMG + y * WW + x;
    unsigned a[C2];
    float ssq1 = 0.f;
#pragma unroll
    for (int c2 = 0; c2 < C2; ++c2) {
        float u0 = f1r[(2 * c2) * HW];
        float u1 = f1r[(2 * c2 + 1) * HW];
        ssq1 = fmaf(u0, u0, fmaf(u1, u1, ssq1));
        a[c2] = pk(u0, u1);
    }

    // ---- stage f2 row y2 into LDS packed [c2][72], zero pads ----
    const float* f2r = f2 + b * IMG + y2 * WW;
#pragma unroll
    for (int it = 0; it < 8; ++it) {
        int item = x + it * 64;        // 512 items: (c2, k)
        int c2 = item >> 4, k = item & 15;
        const float* p = f2r + 4 * k;
        float4 va = *(const float4*)(p + (2 * c2) * HW);
        float4 vb = *(const float4*)(p + (2 * c2 + 1) * HW);
        uint4 u = {pk(va.x, vb.x), pk(va.y, vb.y), pk(va.z, vb.z), pk(va.w, vb.w)};
        *(uint4*)&sB[c2 * 72 + 4 + 4 * k] = u;
    }
#pragma unroll
    for (int it = 0; it < 4; ++it) {   // 256 pad dwords: cols 0..3 and 68..71
        int j = x + it * 64;
        int c2 = j >> 3, e = j & 7;
        sB[c2 * 72 + (e < 4 ? e : 64 + e)] = 0u;
    }
    __syncthreads();                   // single wave: just a waitcnt

    // ---- main loop: 32 c2 x 9 taps, v_dot2_f32_f16; f2 col ssq on the fly ----
    float acc[PATCH];
#pragma unroll
    for (int i = 0; i < PATCH; ++i) acc[i] = 0.f;
    float ssq2 = 0.f;
#pragma unroll
    for (int c2 = 0; c2 < C2; ++c2) {
        v2h a2 = __builtin_bit_cast(v2h, a[c2]);
        const unsigned* br = &sB[c2 * 72 + x];   // tap dx at padded col x+dx
#pragma unroll
        for (int dx = 0; dx < PATCH; ++dx)
            acc[dx] = __builtin_amdgcn_fdot2(a2, __builtin_bit_cast(v2h, br[dx]),
                                             acc[dx], false);
        v2h c4 = __builtin_bit_cast(v2h, br[4]); // padded col x+4 == real col x
        ssq2 = __builtin_amdgcn_fdot2(c4, c4, ssq2, false);
    }
    sS2[x] = rsqrtf(ssq2 + 1e-6f);
    __syncthreads();                   // intra-wave LDS visibility

    const float s1 = rsqrtf(ssq1 + 1e-6f);
#pragma unroll
    for (int dx = 0; dx < PATCH; ++dx) {
        int col = x + dx - HALF;
        col = min(max(col, 0), WW - 1);          // OOB taps have acc==0
        ob[(dy * PATCH + dx) * HW] = fmaxf(acc[dx] * s1 * sS2[col], 0.f);
    }
}

extern "C" void kernel_launch(void* const* d_in, const int* in_sizes, int n_in,
                              void* d_out, int out_size, void* d_ws, size_t ws_size,
                              hipStream_t stream) {
    const float* f1 = (const float*)d_in[0];
    const float* f2 = (const float*)d_in[1];
    float* out = (float*)d_out;
    (void)d_ws; (void)ws_size;

    corr_kernel<<<BB * HH * PATCH, 64, 0, stream>>>(f1, f2, out);
}

// Round 8
// 66.044 us; speedup vs baseline: 1.0714x; 1.0277x over previous
//
#include <hip/hip_runtime.h>

#define BB 4
#define CC 64
#define C2 32            // channel pairs
#define HH 64
#define WW 64
#define PATCH 9
#define HALF 4
#define P2 81
#define HW 4096
#define IMG (CC * HW)

typedef _Float16 v2h __attribute__((ext_vector_type(2)));

static __device__ __forceinline__ unsigned pk(float a, float b) {
    v2h h = {(_Float16)a, (_Float16)b};
    return __builtin_bit_cast(unsigned, h);
}

// One SINGLE-WAVE block per (b, y, dy): 2304 blocks x 64 threads.
// XCD-aware decode: assuming round-robin xcd = blockIdx % 8, XCD k owns
// y-octave [8k, 8k+8) for all (b, dy) -> its f1/f2 working set (~1.5 MB)
// fits the 4 MB per-XCD L2, so the 9x staging redundancy hits L2 not HBM.
__global__ __launch_bounds__(64) void corr_kernel(const float* __restrict__ f1,
                                                  const float* __restrict__ f2,
                                                  float* __restrict__ out) {
    __shared__ unsigned sB[C2 * 72];   // [c2][72 cols]; cols 0..3,68..71 zero (9.2 KB)
    __shared__ float sS2[64];          // f2 column inverse norms (real cols)

    const int x   = threadIdx.x;       // 0..63
    const int bid = blockIdx.x;
    // swizzled decode: xcd = bid & 7 -> y octave; slot enumerates (b, yo, dy)
    const int xcd = bid & 7;
    const int s   = bid >> 3;          // 0..287
    const int b   = s / 72;
    const int r   = s - b * 72;        // 0..71
    const int yo  = r / 9;
    const int dy  = r - yo * 9;
    const int y   = xcd * 8 + yo;
    const int y2  = y + dy - HALF;

    float* ob = out + b * (P2 * HW) + y * WW + x;

    if ((unsigned)y2 >= HH) {          // whole dy-row out of bounds -> zeros
#pragma unroll
        for (int dx = 0; dx < PATCH; ++dx)
            ob[(dy * PATCH + dx) * HW] = 0.f;
        return;
    }

    // ---- f1 row -> registers: packed f16 pairs + fp32 sumsq ----
    const float* f1r = f1 + b * IMG + y * WW + x;
    unsigned a[C2];
    float ssq1 = 0.f;
#pragma unroll
    for (int c2 = 0; c2 < C2; ++c2) {
        float u0 = f1r[(2 * c2) * HW];
        float u1 = f1r[(2 * c2 + 1) * HW];
        ssq1 = fmaf(u0, u0, fmaf(u1, u1, ssq1));
        a[c2] = pk(u0, u1);
    }

    // ---- stage f2 row y2 into LDS packed [c2][72], zero pads ----
    const float* f2r = f2 + b * IMG + y2 * WW;
#pragma unroll
    for (int it = 0; it < 8; ++it) {
        int item = x + it * 64;        // 512 items: (c2, k)
        int c2 = item >> 4, k = item & 15;
        const float* p = f2r + 4 * k;
        float4 va = *(const float4*)(p + (2 * c2) * HW);
        float4 vb = *(const float4*)(p + (2 * c2 + 1) * HW);
        uint4 u = {pk(va.x, vb.x), pk(va.y, vb.y), pk(va.z, vb.z), pk(va.w, vb.w)};
        *(uint4*)&sB[c2 * 72 + 4 + 4 * k] = u;
    }
#pragma unroll
    for (int it = 0; it < 4; ++it) {   // 256 pad dwords: cols 0..3 and 68..71
        int j = x + it * 64;
        int c2 = j >> 3, e = j & 7;
        sB[c2 * 72 + (e < 4 ? e : 64 + e)] = 0u;
    }
    __syncthreads();                   // single wave: just a waitcnt

    // ---- main loop: 32 c2 x 9 taps, v_dot2_f32_f16; f2 col ssq on the fly ----
    float acc[PATCH];
#pragma unroll
    for (int i = 0; i < PATCH; ++i) acc[i] = 0.f;
    float ssq2 = 0.f;
#pragma unroll
    for (int c2 = 0; c2 < C2; ++c2) {
        v2h a2 = __builtin_bit_cast(v2h, a[c2]);
        const unsigned* br = &sB[c2 * 72 + x];   // tap dx at padded col x+dx
#pragma unroll
        for (int dx = 0; dx < PATCH; ++dx)
            acc[dx] = __builtin_amdgcn_fdot2(a2, __builtin_bit_cast(v2h, br[dx]),
                                             acc[dx], false);
        v2h c4 = __builtin_bit_cast(v2h, br[4]); // padded col x+4 == real col x
        ssq2 = __builtin_amdgcn_fdot2(c4, c4, ssq2, false);
    }
    sS2[x] = rsqrtf(ssq2 + 1e-6f);
    __syncthreads();                   // intra-wave LDS visibility

    const float s1 = rsqrtf(ssq1 + 1e-6f);
#pragma unroll
    for (int dx = 0; dx < PATCH; ++dx) {
        int col = x + dx - HALF;
        col = min(max(col, 0), WW - 1);          // OOB taps have acc==0
        ob[(dy * PATCH + dx) * HW] = fmaxf(acc[dx] * s1 * sS2[col], 0.f);
    }
}

extern "C" void kernel_launch(void* const* d_in, const int* in_sizes, int n_in,
                              void* d_out, int out_size, void* d_ws, size_t ws_size,
                              hipStream_t stream) {
    const float* f1 = (const float*)d_in[0];
    const float* f2 = (const float*)d_in[1];
    float* out = (float*)d_out;
    (void)d_ws; (void)ws_size;

    corr_kernel<<<BB * HH * PATCH, 64, 0, stream>>>(f1, f2, out);
}